// Round 6
// baseline (235.141 us; speedup 1.0000x reference)
//
#include <hip/hip_runtime.h>
#include <hip/hip_bf16.h>
#include <math.h>

#define NWRD 2000

typedef __attribute__((ext_vector_type(8)))  short short8;   // 8 bf16 (4 VGPRs)
typedef __attribute__((ext_vector_type(16))) float f32x16;   // MFMA 32x32 acc

// workspace layout (float offsets)
#define WS_FC2WT 0                         // 256*256 bf16
#define WS_WCODE (WS_FC2WT + 32768)        // 64*6000 f32  ([b][n*3+c])
#define WS_VSB   (WS_WCODE + 384000)       // 256*32 bf16
#define WS_W2T   (WS_VSB + 4096)           // (unused)
#define WS_VCB   (WS_W2T + 1536000)        // 64*128*256 bf16
#define WS_FCEWT (WS_VCB + 1048576)        // 32*256 bf16
#define WS_H0B   (WS_FCEWT + 4096)         // (unused)
#define WS_FCAWB (WS_H0B + 16384)          // 32*256 bf16 (row0=fca_w, rest 0)

__device__ __forceinline__ unsigned short f2bf(float x) {
    unsigned int u = __float_as_uint(x);
    u += 0x7fffu + ((u >> 16) & 1u);       // round-to-nearest-even
    return (unsigned short)(u >> 16);
}
// hardware packed f32->bf16 (RNE), 1 instr per 2 values
__device__ __forceinline__ unsigned int pkbf(float lo, float hi) {
    unsigned int r;
    asm("v_cvt_pk_bf16_f32 %0, %1, %2" : "=v"(r) : "v"(lo), "v"(hi));
    return r;
}

// ================ KPREP: prep jobs + fused wcode GEMM in ONE launch ================
// [0,94): wcode GEMM | [94,1118): vcb | [1118,1150): vsb | [1150,1166): fc2wT | 1166: fcewT+fcawB
#define PR_K2  94
#define PR_VCB (PR_K2 + 1024)
#define PR_VSB (PR_VCB + 32)
#define PR_FC2 (PR_VSB + 16)
#define PREP_N (PR_FC2 + 1)
__global__ __launch_bounds__(256) void kprep(
        const float* __restrict__ vc, unsigned short* __restrict__ vcb,
        const float* __restrict__ w2,
        const float* __restrict__ v, const float* __restrict__ w1,
        const float* __restrict__ b1, const float* __restrict__ b2,
        float* __restrict__ wcode,
        const float* __restrict__ vse_w1, const float* __restrict__ vse_b1,
        const float* __restrict__ vse_w2, const float* __restrict__ vse_b2,
        unsigned short* __restrict__ vsb,
        const float* __restrict__ fc2_w, unsigned short* __restrict__ fc2wT,
        const float* __restrict__ fce_w, unsigned short* __restrict__ fcewT,
        const float* __restrict__ fca_w, unsigned short* __restrict__ fcawB) {
    __shared__ __align__(16) unsigned short smem[10240];   // 20.5 KB unioned scratch
    int bid = blockIdx.x, t = threadIdx.x;
    if (bid < PR_K2) {
        // ---- wcode[64 b][64 n] = relu(v@w1+b1) @ w2[:,slice] + b2, via MFMA
        unsigned short* ha = smem;            // [64][72]
        unsigned short* wb = smem + 4608;     // [64][72]
        int n0 = bid * 64;
        int w = t >> 6, lane = t & 63, l31 = lane & 31, h = lane >> 5;
        int mt = w & 1, nt = w >> 1;
        int kk = t & 63, mg = t >> 6;
        int colc = n0 + kk; if (colc > 5999) colc = 5999;
        f32x16 acc;
#pragma unroll
        for (int i = 0; i < 16; i++) acc[i] = 0.f;
        for (int p = 0; p < 8; p++) {
            int k0 = p * 64;
            // h0 panel: thread owns column kk, 16 rows (m = b index); w1 reads coalesced
            float w1c[7];
#pragma unroll
            for (int q = 0; q < 7; q++) w1c[q] = w1[q*512 + k0 + kk];
            float bbv = b1[k0 + kk];
#pragma unroll
            for (int mm = 0; mm < 16; mm++) {
                int m = mg*16 + mm;           // wave-uniform m -> scalar v loads
                float s = bbv;
#pragma unroll
                for (int q = 0; q < 7; q++) s = fmaf(v[m*7 + q], w1c[q], s);
                ha[m*72 + kk] = f2bf(fmaxf(s, 0.f));
            }
            // w2 panel transpose: coalesced f32 row reads -> bf16 n-major LDS
#pragma unroll
            for (int i = 0; i < 16; i++)
                wb[kk*72 + mg*16 + i] = f2bf(w2[(size_t)(k0 + mg*16 + i)*6000 + colc]);
            __syncthreads();
#pragma unroll
            for (int ks = 0; ks < 4; ks++) {
                short8 af = *(const short8*)(ha + (mt*32 + l31)*72 + ks*16 + h*8);
                short8 bf = *(const short8*)(wb + (nt*32 + l31)*72 + ks*16 + h*8);
                acc = __builtin_amdgcn_mfma_f32_32x32x16_bf16(af, bf, acc, 0, 0, 0);
            }
            __syncthreads();
        }
        int n = n0 + nt*32 + l31;
        if (n < 6000) {
            float bias = b2[n];
#pragma unroll
            for (int i = 0; i < 16; i++) {
                int row = (i & 3) + 8*(i >> 2) + 4*h;
                wcode[(size_t)(mt*32 + row)*6000 + n] = acc[i] + bias;
            }
        }
    } else if (bid < PR_VCB) {
        // ---- view_cell f32 -> bf16
        int i = ((bid - PR_K2) * 256 + t) * 8;
        float4 f0 = *(const float4*)(vc + i);
        float4 f1 = *(const float4*)(vc + i + 4);
        union { short8 v8; unsigned int u[4]; } o;
        o.u[0] = pkbf(f0.x, f0.y); o.u[1] = pkbf(f0.z, f0.w);
        o.u[2] = pkbf(f1.x, f1.y); o.u[3] = pkbf(f1.z, f1.w);
        *(short8*)(vcb + i) = o.v8;
    } else if (bid < PR_VSB) {
        // ---- vs MLP -> bf16
        float* hs = (float*)smem;   // [8][128]
        int blk = bid - PR_VCB;
        int m = t & 127, half = t >> 7;
#pragma unroll
        for (int q = 0; q < 4; q++) {
            int vloc = half*4 + q;
            int vv = blk*8 + vloc;
            float x = (2.f/15.f)*(float)(vv >> 4) - 1.f;
            float y = (2.f/15.f)*(float)(vv & 15) - 1.f;
            float hh = vse_b1[m] + x*vse_w1[m] + y*vse_w1[128 + m];
            hs[vloc*128 + m] = fmaxf(hh, 0.f);
        }
        __syncthreads();
        int vloc = t >> 5, e = t & 31;
        float s = vse_b2[e];
        for (int mm = 0; mm < 128; mm++) s = fmaf(hs[vloc*128 + mm], vse_w2[mm*32 + e], s);
        vsb[(blk*8 + vloc)*32 + e] = f2bf(s);
    } else if (bid < PR_FC2) {
        // ---- fc2_w -> fc2wT (n-major bf16)
        unsigned short (*tile)[72] = (unsigned short(*)[72])smem;
        int b2t = bid - PR_VSB;
        int k0t = (b2t >> 2) * 64, n0t = (b2t & 3) * 64;
        int nl = t & 63, kb = (t >> 6) * 16;
#pragma unroll
        for (int i = 0; i < 16; i++)
            tile[kb + i][nl] = f2bf(fc2_w[(size_t)(k0t + kb + i)*256 + n0t + nl]);
        __syncthreads();
        int kl = t & 63, nb = (t >> 6) * 16;
#pragma unroll
        for (int i = 0; i < 16; i++)
            fc2wT[(size_t)(n0t + nb + i)*256 + k0t + kl] = tile[kl][nb + i];
    } else {
        // ---- fcewT (32x256 bf16, e-major) + fcawB (row0 = fca_w, rest 0)
        int e = t & 31, kb = (t >> 5) * 32;
        unsigned short tmp[32];
#pragma unroll
        for (int i = 0; i < 32; i++) tmp[i] = f2bf(fce_w[(size_t)(kb + i)*32 + e]);
#pragma unroll
        for (int i = 0; i < 4; i++)
            *(short8*)(fcewT + (size_t)e*256 + kb + i*8) = *(short8*)(tmp + i*8);
#pragma unroll
        for (int i = 0; i < 32; i++)
            fcawB[(size_t)e*256 + kb + i] = (e == 0) ? f2bf(fca_w[kb + i]) : (unsigned short)0;
    }
}

// ================ K45: single-chunk blocks, 4 blocks/CU ================
// grid (32 nblk, 64 b) = 2048 blocks, 512 threads (8 waves), ONE 64-word chunk each.
// In-place [64][264] bf16 buffer: h1 -> h2 -> exp-route. 5 barriers total, no loop.
// fc1 reads wcode directly (wave-uniform rows -> broadcast loads, no LDS staging).
// Deferred softmax: route holds raw exp; act/sum applied in einsum epilogue; nt-stores.
// LDS: buf @0 (33792) | embL [64][40] @33792 | redS[8][32] @38912 | actL[64] @39936.
// total 40192 B -> 4 blocks/CU (163840/40192 = 4.07); VGPR ~60 -> 8 waves/SIMD ok.
// NOTE launch_bounds min-waves/EU MUST stay <=4 (r4: at 6, VGPR=40 spill, +88MB HBM).
#define K45_LDS 40192
__global__ __launch_bounds__(512, 4) void k45(
        const unsigned short* __restrict__ vcb,
        const float* __restrict__ wcode,
        const float* __restrict__ fc1_w, const float* __restrict__ fc1_b,
        const unsigned short* __restrict__ fc2wT, const float* __restrict__ fc2_b,
        const float* __restrict__ fca_b_p,
        const unsigned short* __restrict__ fcawB,
        const unsigned short* __restrict__ fcewT, const float* __restrict__ fce_b,
        const unsigned short* __restrict__ vsb,
        float* __restrict__ out) {
    extern __shared__ char lds[];
    unsigned short* buf   = (unsigned short*)lds;             // [64][264]
    unsigned short* embL  = (unsigned short*)(lds + 33792);   // [64][40]
    float* redS   = (float*)(lds + 38912);                    // [8][32]
    float* actL   = (float*)(lds + 39936);                    // [64] raw fca logits
    int t = threadIdx.x;
    int w = t >> 6, lane = t & 63, l31 = lane & 31, h = lane >> 5;
    int b = blockIdx.y;
    int n0 = blockIdx.x * 64;

    // hoisted invariants
    int jq = (t & 63) * 4;
    int mtF = w & 1, nqF = w >> 1;             // fc2: wave = (m-half, n-quarter)
    int colA = nqF*64 + l31, colB = colA + 32;
    float baA = fc2_b[colA], baB = fc2_b[colB];
    float be = fce_b[l31];
    float fcab = fca_b_p[0];
    int ntR = w & 1, vq = w >> 1;              // relation tiling
    int cq = w >> 1, ntE = w & 1;              // einsum tiling
    size_t arowE = ((size_t)(b*128 + cq*32 + l31))*256;

    // ---- P0: fc1 -> buf (h1). wcode rows are wave-uniform -> broadcast loads.
    {
        float4 wa  = *(const float4*)(fc1_w + jq);
        float4 wb4 = *(const float4*)(fc1_w + 256 + jq);
        float4 wc  = *(const float4*)(fc1_w + 512 + jq);
        float4 bb4 = *(const float4*)(fc1_b + jq);
        const float* wrow = wcode + (size_t)b*6000;
#pragma unroll
        for (int rr = 0; rr < 8; rr++) {
            int r = w*8 + rr;
            int i = (n0 + r)*3; if (i > 5997) i = 5997;
            float c0 = wrow[i], c1 = wrow[i+1], c2 = wrow[i+2];
            float v0 = fmaxf(fmaf(c2, wc.x, fmaf(c1, wb4.x, fmaf(c0, wa.x, bb4.x))), 0.f);
            float v1 = fmaxf(fmaf(c2, wc.y, fmaf(c1, wb4.y, fmaf(c0, wa.y, bb4.y))), 0.f);
            float v2 = fmaxf(fmaf(c2, wc.z, fmaf(c1, wb4.z, fmaf(c0, wa.z, bb4.z))), 0.f);
            float v3 = fmaxf(fmaf(c2, wc.w, fmaf(c1, wb4.w, fmaf(c0, wa.w, bb4.w))), 0.f);
            uint2 p;
            p.x = pkbf(v0, v1);
            p.y = pkbf(v2, v3);
            *(uint2*)(buf + r*264 + jq) = p;
        }
    }
    __syncthreads();   // A: h1 ready
    // ---- P1: fc2 MFMA (read-only; wave reads only its m-half of A)
    f32x16 c0a, c1a;
#pragma unroll
    for (int i = 0; i < 16; i++) { c0a[i] = 0.f; c1a[i] = 0.f; }
#pragma unroll 4
    for (int ks = 0; ks < 16; ks++) {
        int k0 = ks*16 + h*8;
        short8 af  = *(const short8*)(buf + (mtF*32 + l31)*264 + k0);
        short8 bf0 = *(const short8*)(fc2wT + (size_t)colA*256 + k0);
        short8 bf1 = *(const short8*)(fc2wT + (size_t)colB*256 + k0);
        c0a = __builtin_amdgcn_mfma_f32_32x32x16_bf16(af, bf0, c0a, 0, 0, 0);
        c1a = __builtin_amdgcn_mfma_f32_32x32x16_bf16(af, bf1, c1a, 0, 0, 0);
    }
    __syncthreads();   // B: all h1 reads done
    // ---- P2: write h2 in place
#pragma unroll
    for (int i = 0; i < 16; i++) {
        int row = (i & 3) + 8*(i >> 2) + 4*h;
        unsigned int pk = pkbf(fmaxf(c0a[i] + baA, 0.f), fmaxf(c1a[i] + baB, 0.f));
        buf[(mtF*32 + row)*264 + colA] = (unsigned short)pk;
        buf[(mtF*32 + row)*264 + colB] = (unsigned short)(pk >> 16);
    }
    __syncthreads();   // C: h2 ready
    // ---- P3: fce (waves 0-1) + fca (waves 2-3) read h2
    if (w < 2) {
        f32x16 ce;
#pragma unroll
        for (int i = 0; i < 16; i++) ce[i] = 0.f;
#pragma unroll 4
        for (int ks = 0; ks < 16; ks++) {
            int k0 = ks*16 + h*8;
            short8 af = *(const short8*)(buf + (w*32 + l31)*264 + k0);
            short8 bf = *(const short8*)(fcewT + (size_t)l31*256 + k0);
            ce = __builtin_amdgcn_mfma_f32_32x32x16_bf16(af, bf, ce, 0, 0, 0);
        }
#pragma unroll
        for (int i = 0; i < 16; i += 2) {
            int row = (i & 3) + 8*(i >> 2) + 4*h;
            unsigned int pk = pkbf(ce[i] + be, ce[i+1] + be);
            embL[(w*32 + row)*40 + l31]     = (unsigned short)pk;
            embL[(w*32 + row + 1)*40 + l31] = (unsigned short)(pk >> 16);
        }
    } else if (w < 4) {
        int m = w - 2;
        f32x16 ca;
#pragma unroll
        for (int i = 0; i < 16; i++) ca[i] = 0.f;
#pragma unroll 4
        for (int ks = 0; ks < 16; ks++) {
            int k0 = ks*16 + h*8;
            short8 af = *(const short8*)(buf + (m*32 + l31)*264 + k0);
            short8 bf = *(const short8*)(fcawB + (size_t)l31*256 + k0);
            ca = __builtin_amdgcn_mfma_f32_32x32x16_bf16(af, bf, ca, 0, 0, 0);
        }
        if (l31 == 0) {
#pragma unroll
            for (int i = 0; i < 16; i++) {
                int row = (i & 3) + 8*(i >> 2) + 4*h;
                actL[m*32 + row] = ca[i];           // raw logit
            }
        }
    }
    __syncthreads();   // D: embL/actL ready; h2 reads done
    // ---- P4: relation (K=32 over embL) + exp + redS + pack raw exp into buf
    {
        int nloc = ntR*32 + l31;
        f32x16 ra[2];
#pragma unroll
        for (int mt = 0; mt < 2; mt++)
#pragma unroll
            for (int i = 0; i < 16; i++) ra[mt][i] = 0.f;
#pragma unroll
        for (int s = 0; s < 2; s++) {
            short8 bfrag = *(const short8*)(embL + nloc*40 + s*16 + h*8);
#pragma unroll
            for (int mt = 0; mt < 2; mt++) {
                int vrow = (vq*2 + mt)*32 + l31;
                short8 afrag = *(const short8*)(vsb + vrow*32 + s*16 + h*8);
                ra[mt] = __builtin_amdgcn_mfma_f32_32x32x16_bf16(afrag, bfrag, ra[mt], 0, 0, 0);
            }
        }
        float sm = 0.f;
#pragma unroll
        for (int mt = 0; mt < 2; mt++)
#pragma unroll
            for (int i = 0; i < 16; i++) {
                float e = __expf(ra[mt][i]);
                ra[mt][i] = e;
                sm += e;
            }
        sm += __shfl_xor(sm, 32);
        if (lane < 32) redS[w*32 + l31] = sm;
        // pack UNNORMALIZED exp route (overwrites h2; no reader until E)
#pragma unroll
        for (int mt = 0; mt < 2; mt++) {
#pragma unroll
            for (int g = 0; g < 4; g++) {
                int vb = (vq*2 + mt)*32 + 8*g + 4*h;
                unsigned int p0 = pkbf(ra[mt][g*4+0], ra[mt][g*4+1]);
                unsigned int p1 = pkbf(ra[mt][g*4+2], ra[mt][g*4+3]);
                *(uint2*)(buf + nloc*264 + vb) = make_uint2(p0, p1);
            }
        }
    }
    __syncthreads();   // E: route, redS ready
    // ---- P5: einsum + deferred (act/sum) scale + nt-store
    {
        f32x16 cc;
#pragma unroll
        for (int i = 0; i < 16; i++) cc[i] = 0.f;
        const unsigned short* rrow = buf + (ntE*32 + l31)*264;
#pragma unroll 4
        for (int ks = 0; ks < 16; ks++) {
            int k0 = ks*16 + h*8;
            short8 bf = *(const short8*)(rrow + k0);
            short8 a0 = *(const short8*)(vcb + arowE + k0);
            cc = __builtin_amdgcn_mfma_f32_32x32x16_bf16(a0, bf, cc, 0, 0, 0);
        }
        int wloc = ntE*32 + l31;
        float smt = 0.f;
#pragma unroll
        for (int q = 0; q < 4; q++) smt += redS[(q*2 + ntE)*32 + l31];
        float al = actL[wloc] + fcab;
        float scale = (1.f / (1.f + __expf(-al))) / smt;
        int ng = n0 + wloc;
        if (ng < NWRD) {
            float* ob = out + (size_t)b*128*NWRD + ng;
#pragma unroll
            for (int i = 0; i < 16; i++) {
                int crow = (i & 3) + 8*(i >> 2) + 4*h;
                __builtin_nontemporal_store(cc[i]*scale,
                                            ob + (size_t)(cq*32 + crow)*NWRD);
            }
        }
    }
}

extern "C" void kernel_launch(void* const* d_in, const int* in_sizes, int n_in,
                              void* d_out, int out_size, void* d_ws, size_t ws_size,
                              hipStream_t stream) {
    const float* view_cell = (const float*)d_in[0];
    const float* v       = (const float*)d_in[1];
    const float* w2c_w1  = (const float*)d_in[2];
    const float* w2c_b1  = (const float*)d_in[3];
    const float* w2c_w2  = (const float*)d_in[4];
    const float* w2c_b2  = (const float*)d_in[5];
    const float* fc1_w   = (const float*)d_in[6];
    const float* fc1_b   = (const float*)d_in[7];
    const float* fc2_w   = (const float*)d_in[8];
    const float* fc2_b   = (const float*)d_in[9];
    const float* fca_w   = (const float*)d_in[10];
    const float* fca_b   = (const float*)d_in[11];
    const float* fce_w   = (const float*)d_in[12];
    const float* fce_b   = (const float*)d_in[13];
    const float* vse_w1  = (const float*)d_in[14];
    const float* vse_b1  = (const float*)d_in[15];
    const float* vse_w2  = (const float*)d_in[16];
    const float* vse_b2  = (const float*)d_in[17];
    float* ws    = (float*)d_ws;
    unsigned short* fc2wT = (unsigned short*)(ws + WS_FC2WT);
    float* wcode = ws + WS_WCODE;
    unsigned short* vsb   = (unsigned short*)(ws + WS_VSB);
    unsigned short* vcb   = (unsigned short*)(ws + WS_VCB);
    unsigned short* fcewT = (unsigned short*)(ws + WS_FCEWT);
    unsigned short* fcawB = (unsigned short*)(ws + WS_FCAWB);
    float* out   = (float*)d_out;

    kprep<<<PREP_N, 256, 0, stream>>>(view_cell, vcb,
                                      w2c_w2, v, w2c_w1, w2c_b1, w2c_b2, wcode,
                                      vse_w1, vse_b1, vse_w2, vse_b2, vsb,
                                      fc2_w, fc2wT, fce_w, fcewT, fca_w, fcawB);
    (void)hipFuncSetAttribute((const void*)k45,
                              hipFuncAttributeMaxDynamicSharedMemorySize, K45_LDS);
    dim3 g45(32, 64);
    k45<<<g45, 512, K45_LDS, stream>>>(vcb, wcode, fc1_w, fc1_b, fc2wT, fc2_b,
                                       fca_b, fcawB, fcewT, fce_b, vsb, out);
}